// Round 4
// baseline (168.337 us; speedup 1.0000x reference)
//
#include <hip/hip_runtime.h>
#include <math.h>

namespace {

typedef __bf16 bf16_t;
typedef bf16_t bf16x8 __attribute__((ext_vector_type(8)));
typedef bf16_t bf16x4 __attribute__((ext_vector_type(4)));
typedef bf16_t bf16x2 __attribute__((ext_vector_type(2)));
typedef float f32x4 __attribute__((ext_vector_type(4)));

constexpr int L = 1024;
constexpr int H = 8;
constexpr int E = 64;
constexpr int HE = H * E;            // 512
constexpr int BH = 16;
constexpr size_t PL = (size_t)BH * L * E;  // 1,048,576 elems per plane
constexpr float LOG2E = 1.4426950408889634f;
constexpr float LN2 = 0.6931471805599453f;

__device__ __forceinline__ float rcp_fast(float x) { return __builtin_amdgcn_rcpf(x); }
__device__ __forceinline__ float exp2_fast(float x) { return __builtin_amdgcn_exp2f(x); }
__device__ __forceinline__ float log2_fast(float x) { return __builtin_amdgcn_logf(x); }
__device__ __forceinline__ f32x4 mfma16(bf16x8 a, bf16x8 b, f32x4 c) {
  return __builtin_amdgcn_mfma_f32_16x16x32_bf16(a, b, c, 0, 0, 0);
}
__device__ __forceinline__ void split4(float4 x, bf16x4& hv, bf16x4& lv) {
  hv[0] = (bf16_t)x.x; lv[0] = (bf16_t)(x.x - (float)hv[0]);
  hv[1] = (bf16_t)x.y; lv[1] = (bf16_t)(x.y - (float)hv[1]);
  hv[2] = (bf16_t)x.z; lv[2] = (bf16_t)(x.z - (float)hv[2]);
  hv[3] = (bf16_t)x.w; lv[3] = (bf16_t)(x.w - (float)hv[3]);
}

// ===========================================================================
// Prep + entr zero-init fused. Blocks [0,512): Q,K -> bf16 hi/lo planes
// [bh][l][e], V -> VT bf16 [bh][e][s], 32-row chunks (2x parallelism of R3).
// Blocks [512,528): zero entr.
// ===========================================================================
__global__ __launch_bounds__(256) void k_prep(
    const float* __restrict__ q, const float* __restrict__ k,
    const float* __restrict__ v, bf16_t* __restrict__ ws,
    float* __restrict__ entr)
{
  const int bid = blockIdx.x;
  if (bid >= 512) {  // zero-init entr: 16 blocks * 256 thr * 4 f32 = 16384
    const int idx = (bid - 512) * 256 + threadIdx.x;
    *(float4*)(entr + (size_t)idx * 4) = make_float4(0.f, 0.f, 0.f, 0.f);
    return;
  }
  bf16_t* Qh = ws;
  bf16_t* Ql = ws + PL;
  bf16_t* Kh = ws + 2 * PL;
  bf16_t* Kl = ws + 3 * PL;
  bf16_t* VT = ws + 4 * PL;
  const int bh = bid >> 5, chunk = bid & 31;   // 32-row chunks
  const int b = bh >> 3, h = bh & 7;
  const int tid = threadIdx.x, t8 = tid >> 4, c4 = tid & 15;
  __shared__ bf16_t Vb[64][40];  // [e][l-local 32 + pad8] (row stride 80B, 16B-aligned)

#pragma unroll
  for (int pass = 0; pass < 2; ++pass) {
    const int row = chunk * 32 + pass * 16 + t8;
    const size_t gin = ((size_t)(b * L + row) * H + h) * E + c4 * 4;
    const size_t gout = ((size_t)bh * L + row) * E + c4 * 4;
    float4 q4 = *(const float4*)(q + gin);
    float4 k4 = *(const float4*)(k + gin);
    float4 v4 = *(const float4*)(v + gin);
    bf16x4 hv, lv;
    split4(q4, hv, lv);
    *(bf16x4*)(Qh + gout) = hv; *(bf16x4*)(Ql + gout) = lv;
    split4(k4, hv, lv);
    *(bf16x4*)(Kh + gout) = hv; *(bf16x4*)(Kl + gout) = lv;
    const int sl = pass * 16 + t8;
    Vb[c4 * 4 + 0][sl] = (bf16_t)v4.x;
    Vb[c4 * 4 + 1][sl] = (bf16_t)v4.y;
    Vb[c4 * 4 + 2][sl] = (bf16_t)v4.z;
    Vb[c4 * 4 + 3][sl] = (bf16_t)v4.w;
  }
  __syncthreads();
  {
    const int e = tid >> 2, ch = tid & 3;    // 64 e-rows x 4 chunks of 8
    bf16x8 val = *(const bf16x8*)&Vb[e][ch * 8];
    *(bf16x8*)(VT + ((size_t)bh * E + e) * L + chunk * 32 + ch * 8) = val;
  }
}

// ===========================================================================
// k_sym v2: paired strips, TWO J-strips per iteration (R3 post-mortem:
// k_sym ~40us was barrier/latency-heavy at 3 barriers per tile; v2 is 3
// barriers per TWO tiles and gives each lane 8 independent transcendental
// chains instead of 4). 32 strips of 32 rows. Block (I, bh, z): A-side =
// strip I in registers; z=0 handles diag + gaps {1..8}, z=1 handles gaps
// {9..ghi} (ghi=16 for I<16 else 15). Each unordered strip pair ONCE:
// dual QK^T -> att(l,s) direct store (rows I) + att(s,l) mirror store via
// LDS transpose (rows J, full 128B lines). 11 transcendentals per element
// PAIR. Cached stores (R1: NT partial lines doubled WRITE_SIZE). Prefetch
// of next unit issued right after the staging barrier (R0 shielding).
// LDS 46,080B -> 3 blocks/CU.
// ===========================================================================
__global__ __launch_bounds__(256, 3) void k_sym(
    const bf16_t* __restrict__ ws, float* __restrict__ attg,
    float* __restrict__ entr,
    const float* __restrict__ p_lgg, const float* __restrict__ p_ltg,
    const float* __restrict__ p_lgd, const float* __restrict__ p_ltd)
{
  const bf16_t* Qh = ws;
  const bf16_t* Ql = ws + PL;
  const bf16_t* Kh = ws + 2 * PL;
  const bf16_t* Kl = ws + 3 * PL;

  __shared__ __align__(16) bf16_t P_s[4][64][72];   // rows 0..31 = J0, 32..63 = J1
  __shared__ __align__(16) float att2f[2][32][36];  // a2 transpose, per tile

  const int tid = threadIdx.x;
  const int w = tid >> 6, lane = tid & 63;
  const int c = lane & 15, qd = lane >> 4;
  const int lh = w & 1, sh = w >> 1;
  const int I = blockIdx.x, bh = blockIdx.y, z = blockIdx.z;
  const int ghi = (I < 16) ? 16 : 15;
  const int nu = z ? 4 : 5;

  // unit u -> (J0, J1, tile1-valid, diag)
  auto unitJ = [&](int u, int& J0, int& J1, bool& t1, bool& dg) {
    if (z == 0) {
      if (u == 0) { J0 = I; J1 = I; t1 = false; dg = true; }
      else {
        const int g = 2 * u - 1;
        J0 = (I + g) & 31; J1 = (I + g + 1) & 31; t1 = true; dg = false;
      }
    } else {
      const int g = 9 + 2 * u;
      J0 = (I + g) & 31;
      t1 = (g + 1) <= ghi;
      J1 = t1 ? ((I + g + 1) & 31) : J0;
      dg = false;
    }
  };

  const float gg = fminf(fmaxf(__expf(p_lgg[0]), 1e-3f), 20.0f);
  const float tg = fminf(fmaxf(__expf(p_ltg[0]), 1e-3f), 10.0f);
  const float gd = fminf(fmaxf(__expf(p_lgd[0]), 1e-3f), 20.0f);
  const float td = fminf(fmaxf(__expf(p_ltd[0]), 1e-3f), 10.0f);
  // Folded coefficients (scores 1/8 * symmetrize 1/2 = 1/16; tanh via exp2):
  const float A1 = 0.125f * (1.0f / tg) * LOG2E;
  const float A2 = 0.125f * (1.0f / td) * LOG2E;
  const float A3 = 0.125f * gd * (1.0f / td) * LOG2E;
  const float G1 = -gg * LOG2E, G1m2 = -2.0f * G1;
  const float G2 = -gd * LOG2E, G2m2 = -2.0f * G2;

  // A-fragments: Q/K hi+lo rows I*32 + lh*16 + c, held all loop.
  bf16x8 qaf[2][2], kaf[2][2];
  {
    const size_t aro = ((size_t)bh * L + I * 32 + lh * 16 + c) * E;
#pragma unroll
    for (int ks = 0; ks < 2; ++ks) {
      qaf[ks][0] = *(const bf16x8*)(Qh + aro + ks * 32 + qd * 8);
      qaf[ks][1] = *(const bf16x8*)(Ql + aro + ks * 32 + qd * 8);
      kaf[ks][0] = *(const bf16x8*)(Kh + aro + ks * 32 + qd * 8);
      kaf[ks][1] = *(const bf16x8*)(Kl + aro + ks * 32 + qd * 8);
    }
  }

  // Staging: wave w stages plane w for 64 rows (2 strips); lane = row,
  // 128B/row = 8 bf16x8 per lane.
  const bf16_t* planep = (w == 0) ? Kh : (w == 1) ? Kl : (w == 2) ? Qh : Ql;
  const int lrow = lane & 31;     // row within strip
  const int lsel = lane >> 5;     // 0 -> J0, 1 -> J1

  bf16x8 pf[8];
  {
    int J0, J1; bool t1, dg;
    unitJ(0, J0, J1, t1, dg);
    const size_t off = ((size_t)bh * L + (size_t)(lsel ? J1 : J0) * 32 + lrow) * E;
#pragma unroll
    for (int j = 0; j < 8; ++j) pf[j] = *(const bf16x8*)(planep + off + j * 8);
  }

  float entL[4] = {0.f, 0.f, 0.f, 0.f};  // entropy rows I-strip (log2 domain)

  for (int u = 0; u < nu; ++u) {
    int J0, J1; bool t1v, dflag;
    unitJ(u, J0, J1, t1v, dflag);
    const int ntile = t1v ? 2 : 1;
    const int Jv[2] = {J0, J1};

    __syncthreads();   // prior-unit P_s reads + att2f mirror reads done
#pragma unroll
    for (int j = 0; j < 8; ++j) *(bf16x8*)&P_s[w][lane][j * 8] = pf[j];
    __syncthreads();   // staged tiles visible

    // prefetch unit u+1 NOW (formula valid past range; &31 keeps it in-bounds)
    {
      int nJ0, nJ1; bool nt1, ndg;
      unitJ(u + 1, nJ0, nJ1, nt1, ndg);
      const size_t off =
          ((size_t)bh * L + (size_t)(lsel ? nJ1 : nJ0) * 32 + lrow) * E;
#pragma unroll
      for (int j = 0; j < 8; ++j) pf[j] = *(const bf16x8*)(planep + off + j * 8);
    }

    // Dual QK^T for up to 2 tiles. Term order matched so the true diagonal
    // cancels bitwise (d == 0 at l == s).
    f32x4 acc1[2] = {}, acc2[2] = {};
#pragma unroll
    for (int t = 0; t < 2; ++t) {
      if (t < ntile) {
        const int brow = t * 32 + sh * 16 + c;
#pragma unroll
        for (int ks = 0; ks < 2; ++ks) {
          bf16x8 kbh = *(const bf16x8*)&P_s[0][brow][ks * 32 + qd * 8];
          bf16x8 kbl = *(const bf16x8*)&P_s[1][brow][ks * 32 + qd * 8];
          bf16x8 qbh = *(const bf16x8*)&P_s[2][brow][ks * 32 + qd * 8];
          bf16x8 qbl = *(const bf16x8*)&P_s[3][brow][ks * 32 + qd * 8];
          acc1[t] = mfma16(qaf[ks][0], kbh, acc1[t]);
          acc1[t] = mfma16(qaf[ks][0], kbl, acc1[t]);
          acc1[t] = mfma16(qaf[ks][1], kbh, acc1[t]);
          acc2[t] = mfma16(kaf[ks][0], qbh, acc2[t]);
          acc2[t] = mfma16(kaf[ks][1], qbh, acc2[t]);
          acc2[t] = mfma16(kaf[ks][0], qbl, acc2[t]);
        }
      }
    }

    // Transform. Element (t,r): l = I*32+lh*16+qd*4+r, s = Jv[t]*32+sh*16+c.
    float entS[2] = {0.f, 0.f};
#pragma unroll
    for (int t = 0; t < 2; ++t) {
      if (t < ntile) {
        float* arow = attg + ((size_t)bh * L + I * 32 + lh * 16 + qd * 4) * L +
                      (size_t)Jv[t] * 32 + sh * 16;
        if (!dflag) {
          f32x4 a2v;
#pragma unroll
          for (int r = 0; r < 4; ++r) {
            const float u_ = acc1[t][r] + acc2[t][r];    // 16*S_sym
            const float d_ = acc1[t][r] - acc2[t][r];    // 16*A_anti
            const float r1 = rcp_fast(exp2_fast(u_ * A1) + 1.f);
            const float gate = rcp_fast(1.f + exp2_fast(fmaf(r1, G1m2, G1)));
            const float r2 = rcp_fast(exp2_fast(d_ * A2) + 1.f);
            const float dir = rcp_fast(1.f + exp2_fast(fmaf(r2, G2m2, G2)));
            const float tt = fmaf(rcp_fast(exp2_fast(d_ * A3) + 1.f), -2.f, 1.f);
            const float gdp = gate * dir;
            const float a1 = fmaxf(tt, 0.f) * gdp;             // att(l,s)
            const float a2 = fmaxf(-tt, 0.f) * (gate - gdp);   // att(s,l)
            const float la = log2_fast(fmaxf(a1 + a2, 1e-8f)); // one is zero
            entL[r] -= a1 * la;
            entS[t] -= a2 * la;
            arow[(size_t)r * L + c] = a1;
            a2v[r] = a2;
          }
          *(f32x4*)&att2f[t][sh * 16 + c][lh * 16 + qd * 4] = a2v;
        } else {
#pragma unroll
          for (int r = 0; r < 4; ++r) {
            const float u_ = acc1[t][r] + acc2[t][r];
            const float d_ = acc1[t][r] - acc2[t][r];
            const float r1 = rcp_fast(exp2_fast(u_ * A1) + 1.f);
            const float gate = rcp_fast(1.f + exp2_fast(fmaf(r1, G1m2, G1)));
            const float r2 = rcp_fast(exp2_fast(d_ * A2) + 1.f);
            const float dir = rcp_fast(1.f + exp2_fast(fmaf(r2, G2m2, G2)));
            const float tt = fmaf(rcp_fast(exp2_fast(d_ * A3) + 1.f), -2.f, 1.f);
            const float a1 = fmaxf(tt, 0.f) * gate * dir;
            const float la = log2_fast(fmaxf(a1, 1e-8f));
            entL[r] -= a1 * la;
            arow[(size_t)r * L + c] = a1;
          }
        }
      }
    }
    __syncthreads();   // att2f visible block-wide

    if (!dflag) {
      // Mirror tiles: att rows Jv[t]*32+mr, cols I*32..+32, 128B full lines.
      const int mr = tid >> 3, mc = (tid & 7) * 4;
#pragma unroll
      for (int t = 0; t < 2; ++t) {
        if (t < ntile) {
          float* orow = attg + ((size_t)bh * L + (size_t)Jv[t] * 32 + mr) * L +
                        (size_t)I * 32 + mc;
          *(f32x4*)orow = *(const f32x4*)&att2f[t][mr][mc];
        }
      }
      // entS flush: reduce over qd (the 16 l-rows this wave covers).
#pragma unroll
      for (int t = 0; t < 2; ++t) {
        if (t < ntile) {
          float e = entS[t];
          e += __shfl_xor(e, 16);
          e += __shfl_xor(e, 32);
          if (lane < 16)
            atomicAdd(entr + (size_t)bh * L + (size_t)Jv[t] * 32 + sh * 16 + c,
                      e * LN2);
        }
      }
    }
  }

  // entL flush: reduce over c (s-cols), accumulated across all units.
#pragma unroll
  for (int r = 0; r < 4; ++r) {
    float e = entL[r];
    e += __shfl_xor(e, 1);
    e += __shfl_xor(e, 2);
    e += __shfl_xor(e, 4);
    e += __shfl_xor(e, 8);
    if (c == 0)
      atomicAdd(entr + (size_t)bh * L + I * 32 + lh * 16 + qd * 4 + r, e * LN2);
  }
}

// ===========================================================================
// k_pv v3: Vout = att @ V with ZERO LDS and ZERO barriers (R3 post-mortem:
// v2's 32 barriers around 4-MFMA phases were latency-bound, ~24us). The
// MFMA A-fragment (A[row=c][k=qd*8..+8]) is contiguous in the att f32 row:
// each lane loads its fragment directly from global (16 rows x 128B
// segments per instr, 100% line efficiency, L3-resident), converts f32->
// bf16 in-register (same cast as before, bit-identical), and streams
// MFMAs. grid (32 lt, 16 bh), 256 thr; wave w: l-half w&1, e-half w>>1.
// ===========================================================================
__global__ __launch_bounds__(256, 4) void k_pv(
    const bf16_t* __restrict__ ws, const float* __restrict__ attg,
    float* __restrict__ Vout)
{
  const bf16_t* VT = ws + 4 * PL;
  const int tid = threadIdx.x;
  const int w = tid >> 6, lane = tid & 63;
  const int c = lane & 15, qd = lane >> 4;
  const int mh = w & 1, eh = w >> 1;
  const int lt = blockIdx.x, bh = blockIdx.y;
  const int b = bh >> 3, h = bh & 7;
  const int l0 = lt * 32 + mh * 16;

  const float* arow = attg + ((size_t)bh * L + l0 + c) * L + qd * 8;
  const bf16_t* vrow = VT + ((size_t)bh * E + eh * 32 + c) * L + qd * 8;

  f32x4 acc[2] = {};
#pragma unroll 4
  for (int st = 0; st < 16; ++st) {
#pragma unroll
    for (int ks = 0; ks < 2; ++ks) {
      const int off = st * 64 + ks * 32;
      f32x4 a0 = *(const f32x4*)(arow + off);
      f32x4 a1 = *(const f32x4*)(arow + off + 4);
      bf16x8 av;
      av[0] = (bf16_t)a0[0]; av[1] = (bf16_t)a0[1];
      av[2] = (bf16_t)a0[2]; av[3] = (bf16_t)a0[3];
      av[4] = (bf16_t)a1[0]; av[5] = (bf16_t)a1[1];
      av[6] = (bf16_t)a1[2]; av[7] = (bf16_t)a1[3];
      bf16x8 b0 = *(const bf16x8*)(vrow + off);
      bf16x8 b1 = *(const bf16x8*)(vrow + (size_t)16 * L + off);
      acc[0] = mfma16(av, b0, acc[0]);
      acc[1] = mfma16(av, b1, acc[1]);
    }
  }
#pragma unroll
  for (int n = 0; n < 2; ++n)
#pragma unroll
    for (int r = 0; r < 4; ++r)
      Vout[((size_t)(b * L + l0 + qd * 4 + r) * H + h) * E +
           eh * 32 + n * 16 + c] = acc[n][r];
}

// ===========================================================================
// Fallback (R2 kernel) if ws_size is too small for the planes.
// ===========================================================================
__device__ __forceinline__ float tanh_fast(float x) {
  return 1.0f - 2.0f * rcp_fast(__expf(2.0f * x) + 1.0f);
}
__device__ __forceinline__ float sigm_fast(float x) {
  return rcp_fast(1.0f + __expf(-x));
}
__device__ __forceinline__ void split_store(bf16_t* hi, bf16_t* lo, float4 x) {
  bf16x4 hv, lv;
  split4(x, hv, lv);
  *(bf16x4*)hi = hv;
  *(bf16x4*)lo = lv;
}

__global__ __launch_bounds__(128, 1) void fused_attn(
    const float* __restrict__ q, const float* __restrict__ kk,
    const float* __restrict__ v,
    float* __restrict__ Vout, float* __restrict__ attg, float* __restrict__ entr,
    const float* __restrict__ p_lgg, const float* __restrict__ p_ltg,
    const float* __restrict__ p_lgd, const float* __restrict__ p_ltd)
{
  constexpr int TM = 32;
  __shared__ bf16_t Qa_hi[TM][72], Qa_lo[TM][72];
  __shared__ bf16_t Ka_hi[TM][72], Ka_lo[TM][72];
  __shared__ bf16_t KQ_hi[64][72], KQ_lo[64][72];
  __shared__ bf16_t Vts[64][72];
  __shared__ float  T2ex[2][64][17];
  __shared__ bf16_t attLs[2][16][72];

  const int tid = threadIdx.x;
  const int w = tid >> 6;
  const int lane = tid & 63;
  const int c = lane & 15;
  const int qd = lane >> 4;
  const int t8 = tid >> 4;
  const int c4 = tid & 15;
  const int lt = blockIdx.x;
  const int bh = blockIdx.y;
  const int b = bh >> 3, h = bh & 7;
  const int l0 = lt * TM;

  const float gg = fminf(fmaxf(__expf(p_lgg[0]), 1e-3f), 20.0f);
  const float tg = fminf(fmaxf(__expf(p_ltg[0]), 1e-3f), 10.0f);
  const float gd = fminf(fmaxf(__expf(p_lgd[0]), 1e-3f), 20.0f);
  const float td = fminf(fmaxf(__expf(p_ltd[0]), 1e-3f), 10.0f);
  const float inv_tg = 1.0f / tg;
  const float inv_td = 1.0f / td;
  const float gd_inv_td = gd * inv_td;

  const float* qlbase = q  + ((size_t)(b * L + l0) * H + h) * E;
  const float* qsbase = q  + ((size_t)b * L * H + h) * E;
  const float* kbase  = kk + ((size_t)b * L * H + h) * E;
  const float* vbase  = v  + ((size_t)b * L * H + h) * E;

#pragma unroll
  for (int i = 0; i < 4; ++i) {
    int r = t8 + 8 * i;
    float4 qa = *(const float4*)(qlbase + (size_t)r * HE + c4 * 4);
    float4 ka = *(const float4*)(kbase + (size_t)(l0 + r) * HE + c4 * 4);
    split_store(&Qa_hi[r][c4 * 4], &Qa_lo[r][c4 * 4], qa);
    split_store(&Ka_hi[r][c4 * 4], &Ka_lo[r][c4 * 4], ka);
  }

  float4 kpre[8], qpre[8];
  float vpre[32];
#pragma unroll
  for (int i = 0; i < 8; ++i)
    kpre[i] = *(const float4*)(kbase + (size_t)(t8 + 8 * i) * HE + c4 * 4);
#pragma unroll
  for (int i = 0; i < 8; ++i)
    qpre[i] = *(const float4*)(qsbase + (size_t)(t8 + 8 * i) * HE + c4 * 4);
#pragma unroll
  for (int j = 0; j < 32; ++j)
    vpre[j] = vbase[(size_t)(w * 32 + j) * HE + lane];

  __syncthreads();

  bf16x8 qaf[2][2], kaf[2][2];
#pragma unroll
  for (int ks = 0; ks < 2; ++ks) {
    qaf[ks][0] = *(const bf16x8*)&Qa_hi[w * 16 + c][ks * 32 + qd * 8];
    qaf[ks][1] = *(const bf16x8*)&Qa_lo[w * 16 + c][ks * 32 + qd * 8];
    kaf[ks][0] = *(const bf16x8*)&Ka_hi[w * 16 + c][ks * 32 + qd * 8];
    kaf[ks][1] = *(const bf16x8*)&Ka_lo[w * 16 + c][ks * 32 + qd * 8];
  }

  f32x4 accv[4] = {};
  float ent[4] = {0.f, 0.f, 0.f, 0.f};
  const int gl_base = l0 + w * 16 + qd * 4;

  for (int it = 0; it < 16; ++it) {
    const int s0 = it * 64;
    const int snext = ((it + 1) & 15) * 64;

    __syncthreads();
#pragma unroll
    for (int i = 0; i < 8; ++i) {
      int r = t8 + 8 * i;
      split_store(&KQ_hi[r][c4 * 4], &KQ_lo[r][c4 * 4], kpre[i]);
    }
#pragma unroll
    for (int j = 0; j < 16; ++j) {
      bf16x2 p;
      p[0] = (bf16_t)vpre[2 * j];
      p[1] = (bf16_t)vpre[2 * j + 1];
      *(bf16x2*)&Vts[lane][w * 32 + 2 * j] = p;
    }
    __syncthreads();

#pragma unroll
    for (int i = 0; i < 8; ++i)
      kpre[i] = *(const float4*)(kbase + (size_t)(snext + t8 + 8 * i) * HE + c4 * 4);
#pragma unroll
    for (int j = 0; j < 32; ++j)
      vpre[j] = vbase[(size_t)(snext + w * 32 + j) * HE + lane];

    f32x4 acc1[4] = {};
#pragma unroll
    for (int nt = 0; nt < 4; ++nt) {
#pragma unroll
      for (int ks = 0; ks < 2; ++ks) {
        bf16x8 bhv = *(const bf16x8*)&KQ_hi[nt * 16 + c][ks * 32 + qd * 8];
        bf16x8 blv = *(const bf16x8*)&KQ_lo[nt * 16 + c][ks * 32 + qd * 8];
        acc1[nt] = mfma16(qaf[ks][0], bhv, acc1[nt]);
        acc1[nt] = mfma16(qaf[ks][0], blv, acc1[nt]);
        acc1[nt] = mfma16(qaf[ks][1], bhv, acc1[nt]);
      }
    }
    __syncthreads();

#pragma unroll
    for (int i = 0; i < 8; ++i) {
      int r = t8 + 8 * i;
      split_store(&KQ_hi[r][c4 * 4], &KQ_lo[r][c4 * 4], qpre[i]);
    }
    __syncthreads();

#pragma unroll
    for (int i = 0; i < 8; ++i)
      qpre[i] = *(const float4*)(qsbase + (size_t)(snext + t8 + 8 * i) * HE + c4 * 4);

    f32x4 acc2[4] = {};
#pragma unroll
    for (int mt = 0; mt < 4; ++mt) {
#pragma unroll
      for (int ks = 0; ks < 2; ++ks) {
        bf16x8 ahv = *(const bf16x8*)&KQ_hi[mt * 16 + c][ks * 32 + qd * 8];
        bf16x8 alv = *(const bf16x8*)&KQ_lo[mt * 16 + c][ks * 32 + qd * 8];
        acc2[mt] = mfma16(ahv, kaf[ks][0], acc2[mt]);
        acc2[mt] = mfma16(ahv, kaf[ks][1], acc2[mt]);
        acc2[mt] = mfma16(alv, kaf[ks][0], acc2[mt]);
      }
    }

#pragma unroll
    for (int mt = 0; mt < 4; ++mt)
#pragma unroll
      for (int r = 0; r < 4; ++r)
        T2ex[w][mt * 16 + qd * 4 + r][c] = acc2[mt][r];
    __syncthreads();

    float* attrow0 = attg + ((size_t)bh * L + gl_base) * L + s0;
#pragma unroll
    for (int nt = 0; nt < 4; ++nt) {
#pragma unroll
      for (int r = 0; r < 4; ++r) {
        float x = 0.125f * acc1[nt][r];
        float y = 0.125f * T2ex[w][nt * 16 + c][qd * 4 + r];
        float Ss = 0.5f * (x + y);
        float Aa = 0.5f * (x - y);
        float gate = sigm_fast(gg * tanh_fast(Ss * inv_tg));
        float dir  = sigm_fast(gd * tanh_fast(Aa * inv_td));
        float t    = tanh_fast(Aa * gd_inv_td);
        float a = fmaxf(t, 0.0f) * gate * dir;
        ent[r] -= a * __logf(fmaxf(a, 1e-8f));
        attrow0[(size_t)r * L + nt * 16 + c] = a;
        attLs[w][qd * 4 + r][nt * 16 + c] = (bf16_t)a;
      }
    }
    __syncthreads();

#pragma unroll
    for (int ks = 0; ks < 2; ++ks) {
      bf16x8 af = *(const bf16x8*)&attLs[w][c][ks * 32 + qd * 8];
#pragma unroll
      for (int ne = 0; ne < 4; ++ne) {
        bf16x8 bfv = *(const bf16x8*)&Vts[ne * 16 + c][ks * 32 + qd * 8];
        accv[ne] = mfma16(af, bfv, accv[ne]);
      }
    }
  }

#pragma unroll
  for (int r = 0; r < 4; ++r) {
    float* vb = Vout + ((size_t)(b * L + gl_base + r) * H + h) * E;
#pragma unroll
    for (int ne = 0; ne < 4; ++ne) vb[ne * 16 + c] = accv[ne][r];
    float e4 = ent[r];
    e4 += __shfl_xor(e4, 1);
    e4 += __shfl_xor(e4, 2);
    e4 += __shfl_xor(e4, 4);
    e4 += __shfl_xor(e4, 8);
    if (c == 0) entr[(size_t)bh * L + gl_base + r] = e4;
  }
}

}  // namespace

extern "C" void kernel_launch(void* const* d_in, const int* in_sizes, int n_in,
                              void* d_out, int out_size, void* d_ws, size_t ws_size,
                              hipStream_t stream) {
  const float* q = (const float*)d_in[0];
  const float* k = (const float*)d_in[1];
  const float* v = (const float*)d_in[2];
  const float* p_lgg = (const float*)d_in[7];
  const float* p_ltg = (const float*)d_in[8];
  const float* p_lgd = (const float*)d_in[9];
  const float* p_ltd = (const float*)d_in[10];

  float* Vout = (float*)d_out;          // (B,L,H,E)   1,048,576
  float* att  = Vout + 1048576;         // (B,H,L,S)  16,777,216
  float* entr = att + 16777216;         // (B,H,L)        16,384

  const size_t need = 5 * PL * sizeof(bf16_t);  // 10,485,760 B
  if (ws_size >= need) {
    bf16_t* ws = (bf16_t*)d_ws;
    k_prep<<<dim3(528), 256, 0, stream>>>(q, k, v, ws, entr);
    k_sym<<<dim3(32, 16, 2), 256, 0, stream>>>(
        ws, att, entr, p_lgg, p_ltg, p_lgd, p_ltd);
    k_pv<<<dim3(32, 16), 256, 0, stream>>>(ws, att, Vout);
  } else {
    fused_attn<<<dim3(32, 16), 128, 0, stream>>>(
        q, k, v, Vout, att, entr, p_lgg, p_ltg, p_lgd, p_ltd);
  }
}

// Round 5
// 146.940 us; speedup vs baseline: 1.1456x; 1.1456x over previous
//
#include <hip/hip_runtime.h>
#include <math.h>

namespace {

typedef __bf16 bf16_t;
typedef bf16_t bf16x8 __attribute__((ext_vector_type(8)));
typedef bf16_t bf16x4 __attribute__((ext_vector_type(4)));
typedef bf16_t bf16x2 __attribute__((ext_vector_type(2)));
typedef float f32x4 __attribute__((ext_vector_type(4)));

constexpr int L = 1024;
constexpr int H = 8;
constexpr int E = 64;
constexpr int HE = H * E;            // 512
constexpr int BH = 16;
constexpr size_t PL = (size_t)BH * L * E;  // 1,048,576 elems per plane
constexpr float LOG2E = 1.4426950408889634f;
constexpr float LN2 = 0.6931471805599453f;

__device__ __forceinline__ float rcp_fast(float x) { return __builtin_amdgcn_rcpf(x); }
__device__ __forceinline__ float exp2_fast(float x) { return __builtin_amdgcn_exp2f(x); }
__device__ __forceinline__ float log2_fast(float x) { return __builtin_amdgcn_logf(x); }
__device__ __forceinline__ f32x4 mfma16(bf16x8 a, bf16x8 b, f32x4 c) {
  return __builtin_amdgcn_mfma_f32_16x16x32_bf16(a, b, c, 0, 0, 0);
}
__device__ __forceinline__ void split4(float4 x, bf16x4& hv, bf16x4& lv) {
  hv[0] = (bf16_t)x.x; lv[0] = (bf16_t)(x.x - (float)hv[0]);
  hv[1] = (bf16_t)x.y; lv[1] = (bf16_t)(x.y - (float)hv[1]);
  hv[2] = (bf16_t)x.z; lv[2] = (bf16_t)(x.z - (float)hv[2]);
  hv[3] = (bf16_t)x.w; lv[3] = (bf16_t)(x.w - (float)hv[3]);
}

// ===========================================================================
// Prep + zero-init fused. Blocks [0,512): Q,K -> bf16 hi/lo planes
// [bh][l][e], V -> VT bf16 [bh][e][s], 32-row chunks. Blocks [512,1552):
// zero Vout (k_main atomics need it) + entr.
// ===========================================================================
__global__ __launch_bounds__(256) void k_prep(
    const float* __restrict__ q, const float* __restrict__ k,
    const float* __restrict__ v, bf16_t* __restrict__ ws,
    float* __restrict__ Vout, float* __restrict__ entr)
{
  const int bid = blockIdx.x;
  if (bid >= 512) {  // zero-init branch: 1040 blocks
    const int idx = (bid - 512) * 256 + threadIdx.x;
    const float4 z = make_float4(0.f, 0.f, 0.f, 0.f);
    if (idx < 262144) *(float4*)(Vout + (size_t)idx * 4) = z;
    else              *(float4*)(entr + (size_t)(idx - 262144) * 4) = z;
    return;
  }
  bf16_t* Qh = ws;
  bf16_t* Ql = ws + PL;
  bf16_t* Kh = ws + 2 * PL;
  bf16_t* Kl = ws + 3 * PL;
  bf16_t* VT = ws + 4 * PL;
  const int bh = bid >> 5, chunk = bid & 31;   // 32-row chunks
  const int b = bh >> 3, h = bh & 7;
  const int tid = threadIdx.x, t8 = tid >> 4, c4 = tid & 15;
  __shared__ bf16_t Vb[64][40];  // [e][l-local 32 + pad8]

#pragma unroll
  for (int pass = 0; pass < 2; ++pass) {
    const int row = chunk * 32 + pass * 16 + t8;
    const size_t gin = ((size_t)(b * L + row) * H + h) * E + c4 * 4;
    const size_t gout = ((size_t)bh * L + row) * E + c4 * 4;
    float4 q4 = *(const float4*)(q + gin);
    float4 k4 = *(const float4*)(k + gin);
    float4 v4 = *(const float4*)(v + gin);
    bf16x4 hv, lv;
    split4(q4, hv, lv);
    *(bf16x4*)(Qh + gout) = hv; *(bf16x4*)(Ql + gout) = lv;
    split4(k4, hv, lv);
    *(bf16x4*)(Kh + gout) = hv; *(bf16x4*)(Kl + gout) = lv;
    const int sl = pass * 16 + t8;
    Vb[c4 * 4 + 0][sl] = (bf16_t)v4.x;
    Vb[c4 * 4 + 1][sl] = (bf16_t)v4.y;
    Vb[c4 * 4 + 2][sl] = (bf16_t)v4.z;
    Vb[c4 * 4 + 3][sl] = (bf16_t)v4.w;
  }
  __syncthreads();
  {
    const int e = tid >> 2, ch = tid & 3;    // 64 e-rows x 4 chunks of 8
    bf16x8 val = *(const bf16x8*)&Vb[e][ch * 8];
    *(bf16x8*)(VT + ((size_t)bh * E + e) * L + chunk * 32 + ch * 8) = val;
  }
}

// ===========================================================================
// Main fused kernel = R0 winner (136.9us session best) + ONE fix driven by
// the R0/R4 counters: att stores were 4B/lane NT scalars -> 64B partial
// lines -> L2 write-allocate FETCH of ~0.7x att size from HBM (R0: FETCH
// 44.6MB vs ~12MB genuine; R4 k_sym: 72MB) plus NT partial-line WRITE
// amplification (R0: 91MB written for 64MB att). Fix: stage the 32x64 f32
// att tile in LDS (attf), one extra barrier, then flush with full 128B
// lines (64 lanes x 16B = 8 whole lines per instr), nontemporal. Predicted:
// FETCH -> ~12MB, WRITE -> ~70MB, k_main 51.5 -> ~42us.
// 2-barrier K-loop becomes 3-barrier; shielded prefetch retained (issued
// right after the staging barrier, drains a full compute phase later).
// LDS 59,904B -> 2 blocks/CU (runtime occupancy was ~8 waves/CU anyway).
// ===========================================================================
__global__ __launch_bounds__(256, 2) void k_main(
    const bf16_t* __restrict__ ws,
    float* __restrict__ Vout, float* __restrict__ attg, float* __restrict__ entr,
    const float* __restrict__ p_lgg, const float* __restrict__ p_ltg,
    const float* __restrict__ p_lgd, const float* __restrict__ p_ltd)
{
  const bf16_t* Qh = ws;
  const bf16_t* Ql = ws + PL;
  const bf16_t* Kh = ws + 2 * PL;
  const bf16_t* Kl = ws + 3 * PL;
  const bf16_t* VT = ws + 4 * PL;

  // LDS layout (59,904 B): Kh 0 | Kl 9216 | Qh 18432 | Ql 27648 | Vt 36864 |
  // attL 46080 (5120) | attf 51200 (8704). Epilogue `red` aliases offset 0.
  __shared__ __align__(16) char smem[59904];
  bf16_t (*Kh_s)[72] = (bf16_t(*)[72])(smem);
  bf16_t (*Kl_s)[72] = (bf16_t(*)[72])(smem + 9216);
  bf16_t (*Qh_s)[72] = (bf16_t(*)[72])(smem + 18432);
  bf16_t (*Ql_s)[72] = (bf16_t(*)[72])(smem + 27648);
  bf16_t (*Vt_s)[72] = (bf16_t(*)[72])(smem + 36864);
  bf16_t (*attL)[40] = (bf16_t(*)[40])(smem + 46080);  // [64][40]
  float  (*attf)[68] = (float(*)[68])(smem + 51200);   // [32][68] f32 tile

  const int tid = threadIdx.x;
  const int w = tid >> 6, lane = tid & 63;
  const int c = lane & 15, qd = lane >> 4;
  const int lh = w & 1, sh = w >> 1;
  const int lt = blockIdx.x, bh = blockIdx.y, zb = blockIdx.z;
  const int b = bh >> 3, h = bh & 7;
  const int l0 = lt * 32;

  const float gg = fminf(fmaxf(__expf(p_lgg[0]), 1e-3f), 20.0f);
  const float tg = fminf(fmaxf(__expf(p_ltg[0]), 1e-3f), 10.0f);
  const float gd = fminf(fmaxf(__expf(p_lgd[0]), 1e-3f), 20.0f);
  const float td = fminf(fmaxf(__expf(p_ltd[0]), 1e-3f), 10.0f);
  // Folded coefficients (scores 1/8 * symmetrize 1/2 = 1/16):
  const float A1 = 0.125f * (1.0f / tg) * LOG2E;
  const float A2 = 0.125f * (1.0f / td) * LOG2E;
  const float A3 = 0.125f * gd * (1.0f / td) * LOG2E;
  const float G1 = -gg * LOG2E, G1m2 = -2.0f * G1;
  const float G2 = -gd * LOG2E, G2m2 = -2.0f * G2;

  // A-fragments (held all loop): Q/K hi+lo, row l0 + lh*16 + c
  bf16x8 qaf[2][2], kaf[2][2];
  {
    const size_t aro = ((size_t)bh * L + l0 + lh * 16 + c) * E;
#pragma unroll
    for (int ks = 0; ks < 2; ++ks) {
      qaf[ks][0] = *(const bf16x8*)(Qh + aro + ks * 32 + qd * 8);
      qaf[ks][1] = *(const bf16x8*)(Ql + aro + ks * 32 + qd * 8);
      kaf[ks][0] = *(const bf16x8*)(Kh + aro + ks * 32 + qd * 8);
      kaf[ks][1] = *(const bf16x8*)(Kl + aro + ks * 32 + qd * 8);
    }
  }

  // staging slot: row tid>>2, columns (tid&3)*16 .. +15  (two bf16x8/plane)
  const int srow = tid >> 2, scol = (tid & 3) * 16;

  bf16x8 kh8a, kh8b, kl8a, kl8b, qh8a, qh8b, ql8a, ql8b, vt8a, vt8b;
  {
    const int s0 = zb * 4 * 64;
    const size_t off = ((size_t)bh * L + s0 + srow) * E + scol;
    kh8a = *(const bf16x8*)(Kh + off);   kh8b = *(const bf16x8*)(Kh + off + 8);
    kl8a = *(const bf16x8*)(Kl + off);   kl8b = *(const bf16x8*)(Kl + off + 8);
    qh8a = *(const bf16x8*)(Qh + off);   qh8b = *(const bf16x8*)(Qh + off + 8);
    ql8a = *(const bf16x8*)(Ql + off);   ql8b = *(const bf16x8*)(Ql + off + 8);
    const size_t voff = ((size_t)bh * E + srow) * L + s0 + scol;
    vt8a = *(const bf16x8*)(VT + voff);  vt8b = *(const bf16x8*)(VT + voff + 8);
  }

  f32x4 accv[4] = {};
  float ent[4] = {0.f, 0.f, 0.f, 0.f};  // log2 domain

#pragma unroll
  for (int it = 0; it < 4; ++it) {
    const int s0 = (zb * 4 + it) * 64;
    const int s0n = ((zb * 4 + it + 1) & 15) * 64;

    __syncthreads();  // prior-iter LDS reads done (prefetch loads long-complete)
    *(bf16x8*)&Kh_s[srow][scol]     = kh8a;
    *(bf16x8*)&Kh_s[srow][scol + 8] = kh8b;
    *(bf16x8*)&Kl_s[srow][scol]     = kl8a;
    *(bf16x8*)&Kl_s[srow][scol + 8] = kl8b;
    *(bf16x8*)&Qh_s[srow][scol]     = qh8a;
    *(bf16x8*)&Qh_s[srow][scol + 8] = qh8b;
    *(bf16x8*)&Ql_s[srow][scol]     = ql8a;
    *(bf16x8*)&Ql_s[srow][scol + 8] = ql8b;
    *(bf16x8*)&Vt_s[srow][scol]     = vt8a;
    *(bf16x8*)&Vt_s[srow][scol + 8] = vt8b;
    __syncthreads();  // staged tile visible

    // ---- prefetch it+1 NOW: a full compute phase before the next barrier ----
    {
      const size_t off = ((size_t)bh * L + s0n + srow) * E + scol;
      kh8a = *(const bf16x8*)(Kh + off);   kh8b = *(const bf16x8*)(Kh + off + 8);
      kl8a = *(const bf16x8*)(Kl + off);   kl8b = *(const bf16x8*)(Kl + off + 8);
      qh8a = *(const bf16x8*)(Qh + off);   qh8b = *(const bf16x8*)(Qh + off + 8);
      ql8a = *(const bf16x8*)(Ql + off);   ql8b = *(const bf16x8*)(Ql + off + 8);
      const size_t voff = ((size_t)bh * E + srow) * L + s0n + scol;
      vt8a = *(const bf16x8*)(VT + voff);  vt8b = *(const bf16x8*)(VT + voff + 8);
    }

    // ---- dual QK^T: T1 = Q[l]·K[s], T2 = K[l]·Q[s] (same C-layout).
    // Term order matched so the diagonal cancels bitwise (Aa == 0).
    f32x4 acc1[2] = {}, acc2[2] = {};
#pragma unroll
    for (int nt = 0; nt < 2; ++nt) {
      const int brow = sh * 32 + nt * 16 + c;
#pragma unroll
      for (int ks = 0; ks < 2; ++ks) {
        bf16x8 kbh = *(const bf16x8*)&Kh_s[brow][ks * 32 + qd * 8];
        bf16x8 kbl = *(const bf16x8*)&Kl_s[brow][ks * 32 + qd * 8];
        bf16x8 qbh = *(const bf16x8*)&Qh_s[brow][ks * 32 + qd * 8];
        bf16x8 qbl = *(const bf16x8*)&Ql_s[brow][ks * 32 + qd * 8];
        acc1[nt] = mfma16(qaf[ks][0], kbh, acc1[nt]);
        acc1[nt] = mfma16(qaf[ks][0], kbl, acc1[nt]);
        acc1[nt] = mfma16(qaf[ks][1], kbh, acc1[nt]);
        acc2[nt] = mfma16(kaf[ks][0], qbh, acc2[nt]);
        acc2[nt] = mfma16(kaf[ks][1], qbh, acc2[nt]);
        acc2[nt] = mfma16(kaf[ks][0], qbl, acc2[nt]);
      }
    }

    // ---- transform (register-local), att -> LDS (attf + attL), entropy ----
#pragma unroll
    for (int nt = 0; nt < 2; ++nt) {
#pragma unroll
      for (int r = 0; r < 4; ++r) {
        float u = acc1[nt][r] + acc2[nt][r];        // 16*S_sym
        float d = acc1[nt][r] - acc2[nt][r];        // 16*A_anti
        float r1 = rcp_fast(exp2_fast(u * A1) + 1.f);
        float gate = rcp_fast(1.f + exp2_fast(fmaf(r1, G1m2, G1)));
        float r2 = rcp_fast(exp2_fast(d * A2) + 1.f);
        float dir  = rcp_fast(1.f + exp2_fast(fmaf(r2, G2m2, G2)));
        float t    = fmaf(rcp_fast(exp2_fast(d * A3) + 1.f), -2.f, 1.f);
        float a = fmaxf(t, 0.0f) * gate * dir;
        ent[r] -= a * log2_fast(fmaxf(a, 1e-8f));
        attf[lh * 16 + qd * 4 + r][sh * 32 + nt * 16 + c] = a;
        attL[w * 16 + qd * 4 + r][nt * 16 + c] = (bf16_t)a;
      }
    }
    __syncthreads();  // attf/attL complete block-wide

    // ---- flush attf -> global att: full 128B lines, nontemporal ----
    {
      const int fr = tid >> 4, fc = (tid & 15) * 4;
      float* ab = attg + ((size_t)(bh * L + l0) * L) + s0;
      __builtin_nontemporal_store(*(const f32x4*)&attf[fr][fc],
                                  (f32x4*)(ab + (size_t)fr * L + fc));
      __builtin_nontemporal_store(*(const f32x4*)&attf[16 + fr][fc],
                                  (f32x4*)(ab + (size_t)(16 + fr) * L + fc));
    }

    // ---- PV ----
    bf16x8 af = *(const bf16x8*)&attL[w * 16 + c][qd * 8];
#pragma unroll
    for (int ne = 0; ne < 4; ++ne) {
      bf16x8 bv = *(const bf16x8*)&Vt_s[ne * 16 + c][sh * 32 + qd * 8];
      accv[ne] = mfma16(af, bv, accv[ne]);
    }
  }

  // ---- epilogue: combine s-halves, atomic into global (zb-split blocks) ----
  __syncthreads();  // all LDS reads done before red aliases Kh_s
  float (*red)[68] = (float(*)[68])smem;
  if (sh == 1) {
#pragma unroll
    for (int ne = 0; ne < 4; ++ne)
#pragma unroll
      for (int r = 0; r < 4; ++r)
        red[lh * 16 + qd * 4 + r][ne * 16 + c] = accv[ne][r];
  }
  __syncthreads();
  if (sh == 0) {
#pragma unroll
    for (int ne = 0; ne < 4; ++ne)
#pragma unroll
      for (int r = 0; r < 4; ++r) {
        float val = accv[ne][r] + red[lh * 16 + qd * 4 + r][ne * 16 + c];
        atomicAdd(Vout + ((size_t)(b * L + l0 + lh * 16 + qd * 4 + r) * H + h) * E +
                      ne * 16 + c,
                  val);
      }
  }
#pragma unroll
  for (int r = 0; r < 4; ++r) {
    float e = ent[r];
    e += __shfl_xor(e, 1);
    e += __shfl_xor(e, 2);
    e += __shfl_xor(e, 4);
    e += __shfl_xor(e, 8);
    if (c == 0)
      atomicAdd(entr + (size_t)bh * L + l0 + lh * 16 + qd * 4 + r, e * LN2);
  }
}

// ===========================================================================
// Fallback (R2 kernel) if ws_size is too small for the planes.
// ===========================================================================
__device__ __forceinline__ float tanh_fast(float x) {
  return 1.0f - 2.0f * rcp_fast(__expf(2.0f * x) + 1.0f);
}
__device__ __forceinline__ float sigm_fast(float x) {
  return rcp_fast(1.0f + __expf(-x));
}
__device__ __forceinline__ void split_store(bf16_t* hi, bf16_t* lo, float4 x) {
  bf16x4 hv, lv;
  split4(x, hv, lv);
  *(bf16x4*)hi = hv;
  *(bf16x4*)lo = lv;
}

__global__ __launch_bounds__(128, 1) void fused_attn(
    const float* __restrict__ q, const float* __restrict__ kk,
    const float* __restrict__ v,
    float* __restrict__ Vout, float* __restrict__ attg, float* __restrict__ entr,
    const float* __restrict__ p_lgg, const float* __restrict__ p_ltg,
    const float* __restrict__ p_lgd, const float* __restrict__ p_ltd)
{
  constexpr int TM = 32;
  __shared__ bf16_t Qa_hi[TM][72], Qa_lo[TM][72];
  __shared__ bf16_t Ka_hi[TM][72], Ka_lo[TM][72];
  __shared__ bf16_t KQ_hi[64][72], KQ_lo[64][72];
  __shared__ bf16_t Vts[64][72];
  __shared__ float  T2ex[2][64][17];
  __shared__ bf16_t attLs[2][16][72];

  const int tid = threadIdx.x;
  const int w = tid >> 6;
  const int lane = tid & 63;
  const int c = lane & 15;
  const int qd = lane >> 4;
  const int t8 = tid >> 4;
  const int c4 = tid & 15;
  const int lt = blockIdx.x;
  const int bh = blockIdx.y;
  const int b = bh >> 3, h = bh & 7;
  const int l0 = lt * TM;

  const float gg = fminf(fmaxf(__expf(p_lgg[0]), 1e-3f), 20.0f);
  const float tg = fminf(fmaxf(__expf(p_ltg[0]), 1e-3f), 10.0f);
  const float gd = fminf(fmaxf(__expf(p_lgd[0]), 1e-3f), 20.0f);
  const float td = fminf(fmaxf(__expf(p_ltd[0]), 1e-3f), 10.0f);
  const float inv_tg = 1.0f / tg;
  const float inv_td = 1.0f / td;
  const float gd_inv_td = gd * inv_td;

  const float* qlbase = q  + ((size_t)(b * L + l0) * H + h) * E;
  const float* qsbase = q  + ((size_t)b * L * H + h) * E;
  const float* kbase  = kk + ((size_t)b * L * H + h) * E;
  const float* vbase  = v  + ((size_t)b * L * H + h) * E;

#pragma unroll
  for (int i = 0; i < 4; ++i) {
    int r = t8 + 8 * i;
    float4 qa = *(const float4*)(qlbase + (size_t)r * HE + c4 * 4);
    float4 ka = *(const float4*)(kbase + (size_t)(l0 + r) * HE + c4 * 4);
    split_store(&Qa_hi[r][c4 * 4], &Qa_lo[r][c4 * 4], qa);
    split_store(&Ka_hi[r][c4 * 4], &Ka_lo[r][c4 * 4], ka);
  }

  float4 kpre[8], qpre[8];
  float vpre[32];
#pragma unroll
  for (int i = 0; i < 8; ++i)
    kpre[i] = *(const float4*)(kbase + (size_t)(t8 + 8 * i) * HE + c4 * 4);
#pragma unroll
  for (int i = 0; i < 8; ++i)
    qpre[i] = *(const float4*)(qsbase + (size_t)(t8 + 8 * i) * HE + c4 * 4);
#pragma unroll
  for (int j = 0; j < 32; ++j)
    vpre[j] = vbase[(size_t)(w * 32 + j) * HE + lane];

  __syncthreads();

  bf16x8 qaf[2][2], kaf[2][2];
#pragma unroll
  for (int ks = 0; ks < 2; ++ks) {
    qaf[ks][0] = *(const bf16x8*)&Qa_hi[w * 16 + c][ks * 32 + qd * 8];
    qaf[ks][1] = *(const bf16x8*)&Qa_lo[w * 16 + c][ks * 32 + qd * 8];
    kaf[ks][0] = *(const bf16x8*)&Ka_hi[w * 16 + c][ks * 32 + qd * 8];
    kaf[ks][1] = *(const bf16x8*)&Ka_lo[w * 16 + c][ks * 32 + qd * 8];
  }

  f32x4 accv[4] = {};
  float ent[4] = {0.f, 0.f, 0.f, 0.f};
  const int gl_base = l0 + w * 16 + qd * 4;

  for (int it = 0; it < 16; ++it) {
    const int s0 = it * 64;
    const int snext = ((it + 1) & 15) * 64;

    __syncthreads();
#pragma unroll
    for (int i = 0; i < 8; ++i) {
      int r = t8 + 8 * i;
      split_store(&KQ_hi[r][c4 * 4], &KQ_lo[r][c4 * 4], kpre[i]);
    }
#pragma unroll
    for (int j = 0; j < 16; ++j) {
      bf16x2 p;
      p[0] = (bf16_t)vpre[2 * j];
      p[1] = (bf16_t)vpre[2 * j + 1];
      *(bf16x2*)&Vts[lane][w * 32 + 2 * j] = p;
    }
    __syncthreads();

#pragma unroll
    for (int i = 0; i < 8; ++i)
      kpre[i] = *(const float4*)(kbase + (size_t)(snext + t8 + 8 * i) * HE + c4 * 4);
#pragma unroll
    for (int j = 0; j < 32; ++j)
      vpre[j] = vbase[(size_t)(snext + w * 32 + j) * HE + lane];

    f32x4 acc1[4] = {};
#pragma unroll
    for (int nt = 0; nt < 4; ++nt) {
#pragma unroll
      for (int ks = 0; ks < 2; ++ks) {
        bf16x8 bhv = *(const bf16x8*)&KQ_hi[nt * 16 + c][ks * 32 + qd * 8];
        bf16x8 blv = *(const bf16x8*)&KQ_lo[nt * 16 + c][ks * 32 + qd * 8];
        acc1[nt] = mfma16(qaf[ks][0], bhv, acc1[nt]);
        acc1[nt] = mfma16(qaf[ks][0], blv, acc1[nt]);
        acc1[nt] = mfma16(qaf[ks][1], bhv, acc1[nt]);
      }
    }
    __syncthreads();

#pragma unroll
    for (int i = 0; i < 8; ++i) {
      int r = t8 + 8 * i;
      split_store(&KQ_hi[r][c4 * 4], &KQ_lo[r][c4 * 4], qpre[i]);
    }
    __syncthreads();

#pragma unroll
    for (int i = 0; i < 8; ++i)
      qpre[i] = *(const float4*)(qsbase + (size_t)(snext + t8 + 8 * i) * HE + c4 * 4);

    f32x4 acc2[4] = {};
#pragma unroll
    for (int mt = 0; mt < 4; ++mt) {
#pragma unroll
      for (int ks = 0; ks < 2; ++ks) {
        bf16x8 ahv = *(const bf16x8*)&KQ_hi[mt * 16 + c][ks * 32 + qd * 8];
        bf16x8 alv = *(const bf16x8*)&KQ_lo[mt * 16 + c][ks * 32 + qd * 8];
        acc2[mt] = mfma16(ahv, kaf[ks][0], acc2[mt]);
        acc2[mt] = mfma16(ahv, kaf[ks][1], acc2[mt]);
        acc2[mt] = mfma16(alv, kaf[ks][0], acc2[mt]);
      }
    }

#pragma unroll
    for (int mt = 0; mt < 4; ++mt)
#pragma unroll
      for (int r = 0; r < 4; ++r)
        T2ex[w][mt * 16 + qd * 4 + r][c] = acc2[mt][r];
    __syncthreads();

    float* attrow0 = attg + ((size_t)bh * L + gl_base) * L + s0;
#pragma unroll
    for (int nt = 0; nt < 4; ++nt) {
#pragma unroll
      for (int r = 0; r < 4; ++r) {
        float x = 0.125f * acc1[nt][r];
        float y = 0.125f * T2ex[w][nt * 16 + c][qd * 4 + r];
        float Ss = 0.5f * (x + y);
        float Aa = 0.5f * (x - y);
        float gate = sigm_fast(gg * tanh_fast(Ss * inv_tg));
        float dir  = sigm_fast(gd * tanh_fast(Aa * inv_td));
        float t    = tanh_fast(Aa * gd_inv_td);
        float a = fmaxf(t, 0.0f) * gate * dir;
        ent[r] -= a * __logf(fmaxf(a, 1e-8f));
        attrow0[(size_t)r * L + nt * 16 + c] = a;
        attLs[w][qd * 4 + r][nt * 16 + c] = (bf16_t)a;
      }
    }
    __syncthreads();

#pragma unroll
    for (int ks = 0; ks < 2; ++ks) {
      bf16x8 af = *(const bf16x8*)&attLs[w][c][ks * 32 + qd * 8];
#pragma unroll
      for (int ne = 0; ne < 4; ++ne) {
        bf16x8 bfv = *(const bf16x8*)&Vts[ne * 16 + c][ks * 32 + qd * 8];
        accv[ne] = mfma16(af, bfv, accv[ne]);
      }
    }
  }

#pragma unroll
  for (int r = 0; r < 4; ++r) {
    float* vb = Vout + ((size_t)(b * L + gl_base + r) * H + h) * E;
#pragma unroll
    for (int ne = 0; ne < 4; ++ne) vb[ne * 16 + c] = accv[ne][r];
    float e4 = ent[r];
    e4 += __shfl_xor(e4, 1);
    e4 += __shfl_xor(e4, 2);
    e4 += __shfl_xor(e4, 4);
    e4 += __shfl_xor(e4, 8);
    if (c == 0) entr[(size_t)bh * L + gl_base + r] = e4;
  }
}

}  // namespace

extern "C" void kernel_launch(void* const* d_in, const int* in_sizes, int n_in,
                              void* d_out, int out_size, void* d_ws, size_t ws_size,
                              hipStream_t stream) {
  const float* q = (const float*)d_in[0];
  const float* k = (const float*)d_in[1];
  const float* v = (const float*)d_in[2];
  const float* p_lgg = (const float*)d_in[7];
  const float* p_ltg = (const float*)d_in[8];
  const float* p_lgd = (const float*)d_in[9];
  const float* p_ltd = (const float*)d_in[10];

  float* Vout = (float*)d_out;          // (B,L,H,E)   1,048,576
  float* att  = Vout + 1048576;         // (B,H,L,S)  16,777,216
  float* entr = att + 16777216;         // (B,H,L)        16,384

  const size_t need = 5 * PL * sizeof(bf16_t);  // 10,485,760 B
  if (ws_size >= need) {
    bf16_t* ws = (bf16_t*)d_ws;
    k_prep<<<dim3(1552), 256, 0, stream>>>(q, k, v, ws, Vout, entr);
    k_main<<<dim3(32, 16, 4), 256, 0, stream>>>(
        ws, Vout, att, entr, p_lgg, p_ltg, p_lgd, p_ltd);
  } else {
    fused_attn<<<dim3(32, 16), 128, 0, stream>>>(
        q, k, v, Vout, att, entr, p_lgg, p_ltg, p_lgd, p_ltd);
  }
}

// Round 6
// 138.630 us; speedup vs baseline: 1.2143x; 1.0599x over previous
//
#include <hip/hip_runtime.h>
#include <math.h>

namespace {

typedef __bf16 bf16_t;
typedef bf16_t bf16x8 __attribute__((ext_vector_type(8)));
typedef bf16_t bf16x4 __attribute__((ext_vector_type(4)));
typedef bf16_t bf16x2 __attribute__((ext_vector_type(2)));
typedef float f32x4 __attribute__((ext_vector_type(4)));

constexpr int L = 1024;
constexpr int H = 8;
constexpr int E = 64;
constexpr int HE = H * E;            // 512
constexpr int BH = 16;
constexpr size_t PL = (size_t)BH * L * E;  // 1,048,576 elems per plane
constexpr float LOG2E = 1.4426950408889634f;
constexpr float LN2 = 0.6931471805599453f;

__device__ __forceinline__ float rcp_fast(float x) { return __builtin_amdgcn_rcpf(x); }
__device__ __forceinline__ float exp2_fast(float x) { return __builtin_amdgcn_exp2f(x); }
__device__ __forceinline__ float log2_fast(float x) { return __builtin_amdgcn_logf(x); }
__device__ __forceinline__ f32x4 mfma16(bf16x8 a, bf16x8 b, f32x4 c) {
  return __builtin_amdgcn_mfma_f32_16x16x32_bf16(a, b, c, 0, 0, 0);
}
__device__ __forceinline__ void split4(float4 x, bf16x4& hv, bf16x4& lv) {
  hv[0] = (bf16_t)x.x; lv[0] = (bf16_t)(x.x - (float)hv[0]);
  hv[1] = (bf16_t)x.y; lv[1] = (bf16_t)(x.y - (float)hv[1]);
  hv[2] = (bf16_t)x.z; lv[2] = (bf16_t)(x.z - (float)hv[2]);
  hv[3] = (bf16_t)x.w; lv[3] = (bf16_t)(x.w - (float)hv[3]);
}

// ===========================================================================
// Prep + zero-init fused (R4's fast version: 32-row chunks, 2x parallelism
// of the R0 prep). Blocks [0,512): Q,K -> bf16 hi/lo planes [bh][l][e],
// V -> VT bf16 [bh][e][s]. Blocks [512,1552): zero Vout (k_main atomics
// accumulate into it) + entr.
// ===========================================================================
__global__ __launch_bounds__(256) void k_prep(
    const float* __restrict__ q, const float* __restrict__ k,
    const float* __restrict__ v, bf16_t* __restrict__ ws,
    float* __restrict__ Vout, float* __restrict__ entr)
{
  const int bid = blockIdx.x;
  if (bid >= 512) {  // zero-init branch: 1040 blocks
    const int idx = (bid - 512) * 256 + threadIdx.x;
    const float4 z = make_float4(0.f, 0.f, 0.f, 0.f);
    if (idx < 262144) *(float4*)(Vout + (size_t)idx * 4) = z;
    else              *(float4*)(entr + (size_t)(idx - 262144) * 4) = z;
    return;
  }
  bf16_t* Qh = ws;
  bf16_t* Ql = ws + PL;
  bf16_t* Kh = ws + 2 * PL;
  bf16_t* Kl = ws + 3 * PL;
  bf16_t* VT = ws + 4 * PL;
  const int bh = bid >> 5, chunk = bid & 31;   // 32-row chunks
  const int b = bh >> 3, h = bh & 7;
  const int tid = threadIdx.x, t8 = tid >> 4, c4 = tid & 15;
  __shared__ bf16_t Vb[64][40];  // [e][l-local 32 + pad8]

#pragma unroll
  for (int pass = 0; pass < 2; ++pass) {
    const int row = chunk * 32 + pass * 16 + t8;
    const size_t gin = ((size_t)(b * L + row) * H + h) * E + c4 * 4;
    const size_t gout = ((size_t)bh * L + row) * E + c4 * 4;
    float4 q4 = *(const float4*)(q + gin);
    float4 k4 = *(const float4*)(k + gin);
    float4 v4 = *(const float4*)(v + gin);
    bf16x4 hv, lv;
    split4(q4, hv, lv);
    *(bf16x4*)(Qh + gout) = hv; *(bf16x4*)(Ql + gout) = lv;
    split4(k4, hv, lv);
    *(bf16x4*)(Kh + gout) = hv; *(bf16x4*)(Kl + gout) = lv;
    const int sl = pass * 16 + t8;
    Vb[c4 * 4 + 0][sl] = (bf16_t)v4.x;
    Vb[c4 * 4 + 1][sl] = (bf16_t)v4.y;
    Vb[c4 * 4 + 2][sl] = (bf16_t)v4.z;
    Vb[c4 * 4 + 3][sl] = (bf16_t)v4.w;
  }
  __syncthreads();
  {
    const int e = tid >> 2, ch = tid & 3;    // 64 e-rows x 4 chunks of 8
    bf16x8 val = *(const bf16x8*)&Vb[e][ch * 8];
    *(bf16x8*)(VT + ((size_t)bh * E + e) * L + chunk * 32 + ch * 8) = val;
  }
}

// ===========================================================================
// Main fused kernel — EXACT R0 structure (session best 136.9us; R1-R5
// post-mortems: every structural variant lost — pair blocks latency-bound,
// decoupled PV pays L3 re-read, extra-barrier full-line flush pays
// occupancy). 2-barrier K-loop, SHIELDED prefetch (issued right after the
// staging barrier so the vmcnt drain lands a full compute phase later),
// 51,200B LDS -> 3 blocks/CU. ONE addition vs R0: s_setprio(1) around the
// MFMA clusters (T5: +4-7% measured on attn when co-resident blocks sit at
// different loop phases, which 3 blocks/CU gives us).
// ===========================================================================
__global__ __launch_bounds__(256, 3) void k_main(
    const bf16_t* __restrict__ ws,
    float* __restrict__ Vout, float* __restrict__ attg, float* __restrict__ entr,
    const float* __restrict__ p_lgg, const float* __restrict__ p_ltg,
    const float* __restrict__ p_lgd, const float* __restrict__ p_ltd)
{
  const bf16_t* Qh = ws;
  const bf16_t* Ql = ws + PL;
  const bf16_t* Kh = ws + 2 * PL;
  const bf16_t* Kl = ws + 3 * PL;
  const bf16_t* VT = ws + 4 * PL;

  // LDS layout (51,200 B): Kh 0 | Kl 9216 | Qh 18432 | Ql 27648 | Vt 36864 |
  // attL 46080 (5120). Epilogue `red` aliases offset 0.
  __shared__ __align__(16) char smem[51200];
  bf16_t (*Kh_s)[72] = (bf16_t(*)[72])(smem);
  bf16_t (*Kl_s)[72] = (bf16_t(*)[72])(smem + 9216);
  bf16_t (*Qh_s)[72] = (bf16_t(*)[72])(smem + 18432);
  bf16_t (*Ql_s)[72] = (bf16_t(*)[72])(smem + 27648);
  bf16_t (*Vt_s)[72] = (bf16_t(*)[72])(smem + 36864);
  bf16_t (*attL)[40] = (bf16_t(*)[40])(smem + 46080);  // [64][40]: wave w rows w*16..+15

  const int tid = threadIdx.x;
  const int w = tid >> 6, lane = tid & 63;
  const int c = lane & 15, qd = lane >> 4;
  const int lh = w & 1, sh = w >> 1;
  const int lt = blockIdx.x, bh = blockIdx.y, zb = blockIdx.z;
  const int b = bh >> 3, h = bh & 7;
  const int l0 = lt * 32;

  const float gg = fminf(fmaxf(__expf(p_lgg[0]), 1e-3f), 20.0f);
  const float tg = fminf(fmaxf(__expf(p_ltg[0]), 1e-3f), 10.0f);
  const float gd = fminf(fmaxf(__expf(p_lgd[0]), 1e-3f), 20.0f);
  const float td = fminf(fmaxf(__expf(p_ltd[0]), 1e-3f), 10.0f);
  // Folded coefficients (scores 1/8 * symmetrize 1/2 = 1/16):
  const float A1 = 0.125f * (1.0f / tg) * LOG2E;
  const float A2 = 0.125f * (1.0f / td) * LOG2E;
  const float A3 = 0.125f * gd * (1.0f / td) * LOG2E;
  const float G1 = -gg * LOG2E, G1m2 = -2.0f * G1;
  const float G2 = -gd * LOG2E, G2m2 = -2.0f * G2;

  // A-fragments (held all loop): Q/K hi+lo, row l0 + lh*16 + c
  bf16x8 qaf[2][2], kaf[2][2];
  {
    const size_t aro = ((size_t)bh * L + l0 + lh * 16 + c) * E;
#pragma unroll
    for (int ks = 0; ks < 2; ++ks) {
      qaf[ks][0] = *(const bf16x8*)(Qh + aro + ks * 32 + qd * 8);
      qaf[ks][1] = *(const bf16x8*)(Ql + aro + ks * 32 + qd * 8);
      kaf[ks][0] = *(const bf16x8*)(Kh + aro + ks * 32 + qd * 8);
      kaf[ks][1] = *(const bf16x8*)(Kl + aro + ks * 32 + qd * 8);
    }
  }

  // staging slot: row tid>>2, columns (tid&3)*16 .. +15  (two bf16x8/plane)
  const int srow = tid >> 2, scol = (tid & 3) * 16;

  bf16x8 kh8a, kh8b, kl8a, kl8b, qh8a, qh8b, ql8a, ql8b, vt8a, vt8b;
  {
    const int s0 = zb * 4 * 64;
    const size_t off = ((size_t)bh * L + s0 + srow) * E + scol;
    kh8a = *(const bf16x8*)(Kh + off);   kh8b = *(const bf16x8*)(Kh + off + 8);
    kl8a = *(const bf16x8*)(Kl + off);   kl8b = *(const bf16x8*)(Kl + off + 8);
    qh8a = *(const bf16x8*)(Qh + off);   qh8b = *(const bf16x8*)(Qh + off + 8);
    ql8a = *(const bf16x8*)(Ql + off);   ql8b = *(const bf16x8*)(Ql + off + 8);
    const size_t voff = ((size_t)bh * E + srow) * L + s0 + scol;
    vt8a = *(const bf16x8*)(VT + voff);  vt8b = *(const bf16x8*)(VT + voff + 8);
  }

  f32x4 accv[4] = {};
  float ent[4] = {0.f, 0.f, 0.f, 0.f};  // log2 domain

#pragma unroll
  for (int it = 0; it < 4; ++it) {
    const int s0 = (zb * 4 + it) * 64;
    const int s0n = ((zb * 4 + it + 1) & 15) * 64;

    __syncthreads();  // prior-iter LDS reads done (prefetch loads long-complete)
    *(bf16x8*)&Kh_s[srow][scol]     = kh8a;
    *(bf16x8*)&Kh_s[srow][scol + 8] = kh8b;
    *(bf16x8*)&Kl_s[srow][scol]     = kl8a;
    *(bf16x8*)&Kl_s[srow][scol + 8] = kl8b;
    *(bf16x8*)&Qh_s[srow][scol]     = qh8a;
    *(bf16x8*)&Qh_s[srow][scol + 8] = qh8b;
    *(bf16x8*)&Ql_s[srow][scol]     = ql8a;
    *(bf16x8*)&Ql_s[srow][scol + 8] = ql8b;
    *(bf16x8*)&Vt_s[srow][scol]     = vt8a;
    *(bf16x8*)&Vt_s[srow][scol + 8] = vt8b;
    __syncthreads();  // staged tile visible

    // ---- prefetch it+1 NOW: a full compute phase before the next barrier ----
    {
      const size_t off = ((size_t)bh * L + s0n + srow) * E + scol;
      kh8a = *(const bf16x8*)(Kh + off);   kh8b = *(const bf16x8*)(Kh + off + 8);
      kl8a = *(const bf16x8*)(Kl + off);   kl8b = *(const bf16x8*)(Kl + off + 8);
      qh8a = *(const bf16x8*)(Qh + off);   qh8b = *(const bf16x8*)(Qh + off + 8);
      ql8a = *(const bf16x8*)(Ql + off);   ql8b = *(const bf16x8*)(Ql + off + 8);
      const size_t voff = ((size_t)bh * E + srow) * L + s0n + scol;
      vt8a = *(const bf16x8*)(VT + voff);  vt8b = *(const bf16x8*)(VT + voff + 8);
    }

    // ---- dual QK^T: T1 = Q[l]·K[s], T2 = K[l]·Q[s] (same C-layout).
    // Term order matched so the diagonal cancels bitwise (Aa == 0).
    f32x4 acc1[2] = {}, acc2[2] = {};
    __builtin_amdgcn_s_setprio(1);
#pragma unroll
    for (int nt = 0; nt < 2; ++nt) {
      const int brow = sh * 32 + nt * 16 + c;
#pragma unroll
      for (int ks = 0; ks < 2; ++ks) {
        bf16x8 kbh = *(const bf16x8*)&Kh_s[brow][ks * 32 + qd * 8];
        bf16x8 kbl = *(const bf16x8*)&Kl_s[brow][ks * 32 + qd * 8];
        bf16x8 qbh = *(const bf16x8*)&Qh_s[brow][ks * 32 + qd * 8];
        bf16x8 qbl = *(const bf16x8*)&Ql_s[brow][ks * 32 + qd * 8];
        acc1[nt] = mfma16(qaf[ks][0], kbh, acc1[nt]);
        acc1[nt] = mfma16(qaf[ks][0], kbl, acc1[nt]);
        acc1[nt] = mfma16(qaf[ks][1], kbh, acc1[nt]);
        acc2[nt] = mfma16(kaf[ks][0], qbh, acc2[nt]);
        acc2[nt] = mfma16(kaf[ks][1], qbh, acc2[nt]);
        acc2[nt] = mfma16(kaf[ks][0], qbl, acc2[nt]);
      }
    }
    __builtin_amdgcn_s_setprio(0);

    // ---- transform (register-local), att NT-store, attL, entropy ----
    float* arow = attg + ((size_t)bh * L + l0 + lh * 16 + qd * 4) * L + s0 + sh * 32;
#pragma unroll
    for (int nt = 0; nt < 2; ++nt) {
#pragma unroll
      for (int r = 0; r < 4; ++r) {
        float u = acc1[nt][r] + acc2[nt][r];        // 16*S_sym
        float d = acc1[nt][r] - acc2[nt][r];        // 16*A_anti
        float r1 = rcp_fast(exp2_fast(u * A1) + 1.f);
        float gate = rcp_fast(1.f + exp2_fast(fmaf(r1, G1m2, G1)));
        float r2 = rcp_fast(exp2_fast(d * A2) + 1.f);
        float dir  = rcp_fast(1.f + exp2_fast(fmaf(r2, G2m2, G2)));
        float t    = fmaf(rcp_fast(exp2_fast(d * A3) + 1.f), -2.f, 1.f);
        float a = fmaxf(t, 0.0f) * gate * dir;
        ent[r] -= a * log2_fast(fmaxf(a, 1e-8f));
        __builtin_nontemporal_store(a, arow + (size_t)r * L + nt * 16 + c);
        attL[w * 16 + qd * 4 + r][nt * 16 + c] = (bf16_t)a;
      }
    }
    // wave-local D->A exchange: LDS-only drain; globals stay in flight.
    asm volatile("s_waitcnt lgkmcnt(0)" ::: "memory");

    // ---- PV ----
    bf16x8 af = *(const bf16x8*)&attL[w * 16 + c][qd * 8];
    __builtin_amdgcn_s_setprio(1);
#pragma unroll
    for (int ne = 0; ne < 4; ++ne) {
      bf16x8 bv = *(const bf16x8*)&Vt_s[ne * 16 + c][sh * 32 + qd * 8];
      accv[ne] = mfma16(af, bv, accv[ne]);
    }
    __builtin_amdgcn_s_setprio(0);
  }

  // ---- epilogue: combine s-halves, atomic into global (zb-split blocks) ----
  __syncthreads();  // all LDS reads done before red aliases Kh_s
  float (*red)[68] = (float(*)[68])smem;
  if (sh == 1) {
#pragma unroll
    for (int ne = 0; ne < 4; ++ne)
#pragma unroll
      for (int r = 0; r < 4; ++r)
        red[lh * 16 + qd * 4 + r][ne * 16 + c] = accv[ne][r];
  }
  __syncthreads();
  if (sh == 0) {
#pragma unroll
    for (int ne = 0; ne < 4; ++ne)
#pragma unroll
      for (int r = 0; r < 4; ++r) {
        float val = accv[ne][r] + red[lh * 16 + qd * 4 + r][ne * 16 + c];
        atomicAdd(Vout + ((size_t)(b * L + l0 + lh * 16 + qd * 4 + r) * H + h) * E +
                      ne * 16 + c,
                  val);
      }
  }
#pragma unroll
  for (int r = 0; r < 4; ++r) {
    float e = ent[r];
    e += __shfl_xor(e, 1);
    e += __shfl_xor(e, 2);
    e += __shfl_xor(e, 4);
    e += __shfl_xor(e, 8);
    if (c == 0)
      atomicAdd(entr + (size_t)bh * L + l0 + lh * 16 + qd * 4 + r, e * LN2);
  }
}

// ===========================================================================
// Fallback (R2 kernel) if ws_size is too small for the planes.
// ===========================================================================
__device__ __forceinline__ float tanh_fast(float x) {
  return 1.0f - 2.0f * rcp_fast(__expf(2.0f * x) + 1.0f);
}
__device__ __forceinline__ float sigm_fast(float x) {
  return rcp_fast(1.0f + __expf(-x));
}
__device__ __forceinline__ void split_store(bf16_t* hi, bf16_t* lo, float4 x) {
  bf16x4 hv, lv;
  split4(x, hv, lv);
  *(bf16x4*)hi = hv;
  *(bf16x4*)lo = lv;
}

__global__ __launch_bounds__(128, 1) void fused_attn(
    const float* __restrict__ q, const float* __restrict__ kk,
    const float* __restrict__ v,
    float* __restrict__ Vout, float* __restrict__ attg, float* __restrict__ entr,
    const float* __restrict__ p_lgg, const float* __restrict__ p_ltg,
    const float* __restrict__ p_lgd, const float* __restrict__ p_ltd)
{
  constexpr int TM = 32;
  __shared__ bf16_t Qa_hi[TM][72], Qa_lo[TM][72];
  __shared__ bf16_t Ka_hi[TM][72], Ka_lo[TM][72];
  __shared__ bf16_t KQ_hi[64][72], KQ_lo[64][72];
  __shared__ bf16_t Vts[64][72];
  __shared__ float  T2ex[2][64][17];
  __shared__ bf16_t attLs[2][16][72];

  const int tid = threadIdx.x;
  const int w = tid >> 6;
  const int lane = tid & 63;
  const int c = lane & 15;
  const int qd = lane >> 4;
  const int t8 = tid >> 4;
  const int c4 = tid & 15;
  const int lt = blockIdx.x;
  const int bh = blockIdx.y;
  const int b = bh >> 3, h = bh & 7;
  const int l0 = lt * TM;

  const float gg = fminf(fmaxf(__expf(p_lgg[0]), 1e-3f), 20.0f);
  const float tg = fminf(fmaxf(__expf(p_ltg[0]), 1e-3f), 10.0f);
  const float gd = fminf(fmaxf(__expf(p_lgd[0]), 1e-3f), 20.0f);
  const float td = fminf(fmaxf(__expf(p_ltd[0]), 1e-3f), 10.0f);
  const float inv_tg = 1.0f / tg;
  const float inv_td = 1.0f / td;
  const float gd_inv_td = gd * inv_td;

  const float* qlbase = q  + ((size_t)(b * L + l0) * H + h) * E;
  const float* qsbase = q  + ((size_t)b * L * H + h) * E;
  const float* kbase  = kk + ((size_t)b * L * H + h) * E;
  const float* vbase  = v  + ((size_t)b * L * H + h) * E;

#pragma unroll
  for (int i = 0; i < 4; ++i) {
    int r = t8 + 8 * i;
    float4 qa = *(const float4*)(qlbase + (size_t)r * HE + c4 * 4);
    float4 ka = *(const float4*)(kbase + (size_t)(l0 + r) * HE + c4 * 4);
    split_store(&Qa_hi[r][c4 * 4], &Qa_lo[r][c4 * 4], qa);
    split_store(&Ka_hi[r][c4 * 4], &Ka_lo[r][c4 * 4], ka);
  }

  float4 kpre[8], qpre[8];
  float vpre[32];
#pragma unroll
  for (int i = 0; i < 8; ++i)
    kpre[i] = *(const float4*)(kbase + (size_t)(t8 + 8 * i) * HE + c4 * 4);
#pragma unroll
  for (int i = 0; i < 8; ++i)
    qpre[i] = *(const float4*)(qsbase + (size_t)(t8 + 8 * i) * HE + c4 * 4);
#pragma unroll
  for (int j = 0; j < 32; ++j)
    vpre[j] = vbase[(size_t)(w * 32 + j) * HE + lane];

  __syncthreads();

  bf16x8 qaf[2][2], kaf[2][2];
#pragma unroll
  for (int ks = 0; ks < 2; ++ks) {
    qaf[ks][0] = *(const bf16x8*)&Qa_hi[w * 16 + c][ks * 32 + qd * 8];
    qaf[ks][1] = *(const bf16x8*)&Qa_lo[w * 16 + c][ks * 32 + qd * 8];
    kaf[ks][0] = *(const bf16x8*)&Ka_hi[w * 16 + c][ks * 32 + qd * 8];
    kaf[ks][1] = *(const bf16x8*)&Ka_lo[w * 16 + c][ks * 32 + qd * 8];
  }

  f32x4 accv[4] = {};
  float ent[4] = {0.f, 0.f, 0.f, 0.f};
  const int gl_base = l0 + w * 16 + qd * 4;

  for (int it = 0; it < 16; ++it) {
    const int s0 = it * 64;
    const int snext = ((it + 1) & 15) * 64;

    __syncthreads();
#pragma unroll
    for (int i = 0; i < 8; ++i) {
      int r = t8 + 8 * i;
      split_store(&KQ_hi[r][c4 * 4], &KQ_lo[r][c4 * 4], kpre[i]);
    }
#pragma unroll
    for (int j = 0; j < 16; ++j) {
      bf16x2 p;
      p[0] = (bf16_t)vpre[2 * j];
      p[1] = (bf16_t)vpre[2 * j + 1];
      *(bf16x2*)&Vts[lane][w * 32 + 2 * j] = p;
    }
    __syncthreads();

#pragma unroll
    for (int i = 0; i < 8; ++i)
      kpre[i] = *(const float4*)(kbase + (size_t)(snext + t8 + 8 * i) * HE + c4 * 4);
#pragma unroll
    for (int j = 0; j < 32; ++j)
      vpre[j] = vbase[(size_t)(snext + w * 32 + j) * HE + lane];

    f32x4 acc1[4] = {};
#pragma unroll
    for (int nt = 0; nt < 4; ++nt) {
#pragma unroll
      for (int ks = 0; ks < 2; ++ks) {
        bf16x8 bhv = *(const bf16x8*)&KQ_hi[nt * 16 + c][ks * 32 + qd * 8];
        bf16x8 blv = *(const bf16x8*)&KQ_lo[nt * 16 + c][ks * 32 + qd * 8];
        acc1[nt] = mfma16(qaf[ks][0], bhv, acc1[nt]);
        acc1[nt] = mfma16(qaf[ks][0], blv, acc1[nt]);
        acc1[nt] = mfma16(qaf[ks][1], bhv, acc1[nt]);
      }
    }
    __syncthreads();

#pragma unroll
    for (int i = 0; i < 8; ++i) {
      int r = t8 + 8 * i;
      split_store(&KQ_hi[r][c4 * 4], &KQ_lo[r][c4 * 4], qpre[i]);
    }
    __syncthreads();

#pragma unroll
    for (int i = 0; i < 8; ++i)
      qpre[i] = *(const float4*)(qsbase + (size_t)(snext + t8 + 8 * i) * HE + c4 * 4);

    f32x4 acc2[4] = {};
#pragma unroll
    for (int mt = 0; mt < 4; ++mt) {
#pragma unroll
      for (int ks = 0; ks < 2; ++ks) {
        bf16x8 ahv = *(const bf16x8*)&KQ_hi[mt * 16 + c][ks * 32 + qd * 8];
        bf16x8 alv = *(const bf16x8*)&KQ_lo[mt * 16 + c][ks * 32 + qd * 8];
        acc2[mt] = mfma16(ahv, kaf[ks][0], acc2[mt]);
        acc2[mt] = mfma16(ahv, kaf[ks][1], acc2[mt]);
        acc2[mt] = mfma16(alv, kaf[ks][0], acc2[mt]);
      }
    }

#pragma unroll
    for (int mt = 0; mt < 4; ++mt)
#pragma unroll
      for (int r = 0; r < 4; ++r)
        T2ex[w][mt * 16 + qd * 4 + r][c] = acc2[mt][r];
    __syncthreads();

    float* attrow0 = attg + ((size_t)bh * L + gl_base) * L + s0;
#pragma unroll
    for (int nt = 0; nt < 4; ++nt) {
#pragma unroll
      for (int r = 0; r < 4; ++r) {
        float x = 0.125f * acc1[nt][r];
        float y = 0.125f * T2ex[w][nt * 16 + c][qd * 4 + r];
        float Ss = 0.5f * (x + y);
        float Aa = 0.5f * (x - y);
        float gate = sigm_fast(gg * tanh_fast(Ss * inv_tg));
        float dir  = sigm_fast(gd * tanh_fast(Aa * inv_td));
        float t    = tanh_fast(Aa * gd_inv_td);
        float a = fmaxf(t, 0.0f) * gate * dir;
        ent[r] -= a * __logf(fmaxf(a, 1e-8f));
        attrow0[(size_t)r * L + nt * 16 + c] = a;
        attLs[w][qd * 4 + r][nt * 16 + c] = (bf16_t)a;
      }
    }
    __syncthreads();

#pragma unroll
    for (int ks = 0; ks < 2; ++ks) {
      bf16x8 af = *(const bf16x8*)&attLs[w][c][ks * 32 + qd * 8];
#pragma unroll
      for (int ne = 0; ne < 4; ++ne) {
        bf16x8 bfv = *(const bf16x8*)&Vts[ne * 16 + c][ks * 32 + qd * 8];
        accv[ne] = mfma16(af, bfv, accv[ne]);
      }
    }
  }

#pragma unroll
  for (int r = 0; r < 4; ++r) {
    float* vb = Vout + ((size_t)(b * L + gl_base + r) * H + h) * E;
#pragma unroll
    for (int ne = 0; ne < 4; ++ne) vb[ne * 16 + c] = accv[ne][r];
    float e4 = ent[r];
    e4 += __shfl_xor(e4, 1);
    e4 += __shfl_xor(e4, 2);
    e4 += __shfl_xor(e4, 4);
    e4 += __shfl_xor(e4, 8);
    if (c == 0) entr[(size_t)bh * L + gl_base + r] = e4;
  }
}

}  // namespace

extern "C" void kernel_launch(void* const* d_in, const int* in_sizes, int n_in,
                              void* d_out, int out_size, void* d_ws, size_t ws_size,
                              hipStream_t stream) {
  const float* q = (const float*)d_in[0];
  const float* k = (const float*)d_in[1];
  const float* v = (const float*)d_in[2];
  const float* p_lgg = (const float*)d_in[7];
  const float* p_ltg = (const float*)d_in[8];
  const float* p_lgd = (const float*)d_in[9];
  const float* p_ltd = (const float*)d_in[10];

  float* Vout = (float*)d_out;          // (B,L,H,E)   1,048,576
  float* att  = Vout + 1048576;         // (B,H,L,S)  16,777,216
  float* entr = att + 16777216;         // (B,H,L)        16,384

  const size_t need = 5 * PL * sizeof(bf16_t);  // 10,485,760 B
  if (ws_size >= need) {
    bf16_t* ws = (bf16_t*)d_ws;
    k_prep<<<dim3(1552), 256, 0, stream>>>(q, k, v, ws, Vout, entr);
    k_main<<<dim3(32, 16, 4), 256, 0, stream>>>(
        ws, Vout, att, entr, p_lgg, p_ltg, p_lgd, p_ltd);
  } else {
    fused_attn<<<dim3(32, 16), 128, 0, stream>>>(
        q, k, v, Vout, att, entr, p_lgg, p_ltg, p_lgd, p_ltd);
  }
}